// Round 3
// baseline (2856.113 us; speedup 1.0000x reference)
//
#include <hip/hip_runtime.h>
#include <math.h>

#define BATCH 4
#define NPTS  8192
#define NSAMP 2048
#define KNBR  64
#define EPSF  1e-5f

// ---------------------------------------------------------------------------
// Kernel 0: transpose weights into ws so MLP reads are contiguous scalar loads
// ---------------------------------------------------------------------------
__global__ void prep_kernel(const float* __restrict__ W1, const float* __restrict__ W2,
                            const float* __restrict__ W3,
                            float* __restrict__ W1t, float* __restrict__ W2t,
                            float* __restrict__ W3t) {
    int t = threadIdx.x;
    for (int i = t; i < 64 * 67; i += 256) { int o = i / 67, c = i % 67; W1t[c * 64 + o] = W1[i]; }
    for (int i = t; i < 64 * 64; i += 256) { int o = i >> 6, c = i & 63; W2t[c * 64 + o] = W2[i]; }
    for (int i = t; i < 128 * 64; i += 256) { int o = i >> 6, c = i & 63; W3t[c * 128 + o] = W3[i]; }
}

// ---------------------------------------------------------------------------
// Kernel 1: farthest point sampling — one block per batch, 512 threads
// (8 waves, 2/SIMD), 16 points/thread in registers.
// Exact fp32 (no FMA contraction) to match numpy reference.
// Reduce is all-32-bit: wave float shuffle-max, then ballot(bestd==wmax) ->
// lowest lane (lane order == index order, so this is the exact jnp.argmax
// tie-break) -> one shfl for the index. Block stage: 8 float partials +
// 8 int indices, lowest-wid match wins. ONE __syncthreads per step via
// parity double-buffered partials.
// ---------------------------------------------------------------------------
__global__ __launch_bounds__(512) void fps_kernel(const float* __restrict__ x,
                                                  float* __restrict__ cen_out) {
    const int b = blockIdx.x;
    const int tid = threadIdx.x;
    const int lane = tid & 63;
    const int wid = tid >> 6;
    __shared__ float sx[NPTS], sy[NPTS], sz[NPTS];   // 96 KB
    __shared__ float pd[2][8];
    __shared__ int pi[2][8];

    const float* xb = x + (size_t)b * NPTS * 3;
    for (int i = tid; i < NPTS; i += 512) {
        sx[i] = xb[3 * i + 0];
        sy[i] = xb[3 * i + 1];
        sz[i] = xb[3 * i + 2];
    }
    __syncthreads();

    // 16 points per thread, contiguous: p = tid*16 + j  (j increasing == idx increasing)
    float px[16], py[16], pz[16], dist[16];
#pragma unroll
    for (int j = 0; j < 16; j++) {
        int p = tid * 16 + j;
        px[j] = sx[p]; py[j] = sy[p]; pz[j] = sz[p];
        dist[j] = 1e10f;
    }

    int cur = 0;
    for (int s = 0; s < NSAMP; s++) {
        float cx = sx[cur], cy = sy[cur], cz = sz[cur];
        if (tid == 0) {
            float* o = cen_out + ((size_t)b * NSAMP + s) * 3;
            o[0] = cx; o[1] = cy; o[2] = cz;
        }
        float bestd = -1.0f;
        int bestj = 0;
#pragma unroll
        for (int j = 0; j < 16; j++) {
            float dx = __fsub_rn(px[j], cx);
            float dy = __fsub_rn(py[j], cy);
            float dz = __fsub_rn(pz[j], cz);
            float d = __fadd_rn(__fadd_rn(__fmul_rn(dx, dx), __fmul_rn(dy, dy)), __fmul_rn(dz, dz));
            float dm = fminf(dist[j], d);
            dist[j] = dm;
            if (dm > bestd) { bestd = dm; bestj = j; }   // strict >: lowest idx on tie
        }
        // wave reduce: float max only (32-bit shuffles)
        float w = bestd;
#pragma unroll
        for (int off = 32; off > 0; off >>= 1)
            w = fmaxf(w, __shfl_xor(w, off, 64));
        // index recovery: lowest lane attaining w == lowest point index
        unsigned long long eq = __ballot(bestd == w);
        int src = __ffsll((unsigned long long)eq) - 1;
        int widx = __shfl(tid * 16 + bestj, src, 64);
        const int p = s & 1;
        if (lane == 0) { pd[p][wid] = w; pi[p][wid] = widx; }
        __syncthreads();
        float bmax = pd[p][0];
#pragma unroll
        for (int i = 1; i < 8; i++) bmax = fmaxf(bmax, pd[p][i]);
        int idx = 0;
#pragma unroll
        for (int i = 7; i >= 0; i--)           // lowest matching wid wins
            if (pd[p][i] == bmax) idx = pi[p][i];
        cur = idx;
    }
}

// ---------------------------------------------------------------------------
// Kernel 2: ball query — one wave per centroid, ballot compaction, first-K in
// ascending index order (== top_k(-cand) semantics), -1 padded.
// ---------------------------------------------------------------------------
__global__ __launch_bounds__(256) void ball_kernel(const float* __restrict__ x,
                                                   const float* __restrict__ cen,
                                                   int* __restrict__ idxb) {
    const int wid = threadIdx.x >> 6, lane = threadIdx.x & 63;
    const int id = blockIdx.x * 4 + wid;           // 0..8191 == b*NSAMP+s
    const int b = id >> 11;
    const float r2 = (float)(0.2 * 0.2);
    const float cx = cen[3 * id], cy = cen[3 * id + 1], cz = cen[3 * id + 2];
    const float* xb = x + (size_t)b * NPTS * 3;

    int count = 0;
    for (int base = 0; base < NPTS && count < KNBR; base += 64) {
        int p = base + lane;
        float pxv = xb[3 * p], pyv = xb[3 * p + 1], pzv = xb[3 * p + 2];
        float dx = __fsub_rn(cx, pxv);
        float dy = __fsub_rn(cy, pyv);
        float dz = __fsub_rn(cz, pzv);
        float d2 = __fadd_rn(__fadd_rn(__fmul_rn(dx, dx), __fmul_rn(dy, dy)), __fmul_rn(dz, dz));
        bool hit = d2 < r2;
        unsigned long long m = __ballot(hit);
        if (hit) {
            int pos = count + __popcll(m & ((1ull << lane) - 1ull));
            if (pos < KNBR) idxb[(size_t)id * KNBR + pos] = p;
        }
        count += (int)__popcll(m);
    }
    for (int pos = count + lane; pos < KNBR; pos += 64)
        idxb[(size_t)id * KNBR + pos] = -1;
}

// ---------------------------------------------------------------------------
// Kernel 3: gather + 3x(conv1x1+BN+ReLU) + masked max pool.
// One wave per centroid, lane = neighbor. h1/h2 in registers; weights via
// wave-uniform scalar loads (transposed layout). Layer3 in 4 chunks of 32
// channels with per-wave LDS max-reduction across lanes.
// ---------------------------------------------------------------------------
__global__ __launch_bounds__(256) void mlp_kernel(
    const float* __restrict__ x, const float* __restrict__ xc,
    const float* __restrict__ cen, const int* __restrict__ idxb,
    const float* __restrict__ W1t, const float* __restrict__ b1, const float* __restrict__ g1,
    const float* __restrict__ bt1, const float* __restrict__ m1, const float* __restrict__ v1,
    const float* __restrict__ W2t, const float* __restrict__ b2, const float* __restrict__ g2,
    const float* __restrict__ bt2, const float* __restrict__ m2, const float* __restrict__ v2,
    const float* __restrict__ W3t, const float* __restrict__ b3, const float* __restrict__ g3,
    const float* __restrict__ bt3, const float* __restrict__ m3, const float* __restrict__ v3,
    float* __restrict__ pooled) {
    const int wid = threadIdx.x >> 6, lane = threadIdx.x & 63;
    const int id = blockIdx.x * 4 + wid;            // b*NSAMP + s
    const int b = id >> 11;
    __shared__ float sred[4][64][33];

    int il = idxb[(size_t)id * KNBR + lane];
    bool valid = il >= 0;
    int ik = valid ? il : 0;

    float cx = cen[3 * id], cy = cen[3 * id + 1], cz = cen[3 * id + 2];
    const float* xp = x + ((size_t)b * NPTS + ik) * 3;
    const float* xcp = xc + ((size_t)b * NPTS + ik) * 64;

    // ----- layer 1: 67 -> 64 -----
    float h1[64];
#pragma unroll
    for (int o = 0; o < 64; o++) h1[o] = 0.f;
#pragma unroll
    for (int c4 = 0; c4 < 16; c4++) {
        float4 t = ((const float4*)xcp)[c4];
        float tv0 = t.x, tv1 = t.y, tv2 = t.z, tv3 = t.w;
#pragma unroll
        for (int o = 0; o < 64; o++) h1[o] = fmaf(W1t[(c4 * 4 + 0) * 64 + o], tv0, h1[o]);
#pragma unroll
        for (int o = 0; o < 64; o++) h1[o] = fmaf(W1t[(c4 * 4 + 1) * 64 + o], tv1, h1[o]);
#pragma unroll
        for (int o = 0; o < 64; o++) h1[o] = fmaf(W1t[(c4 * 4 + 2) * 64 + o], tv2, h1[o]);
#pragma unroll
        for (int o = 0; o < 64; o++) h1[o] = fmaf(W1t[(c4 * 4 + 3) * 64 + o], tv3, h1[o]);
    }
    {
        float xl0 = xp[0] - cx, xl1 = xp[1] - cy, xl2 = xp[2] - cz;
#pragma unroll
        for (int o = 0; o < 64; o++) h1[o] = fmaf(W1t[64 * 64 + o], xl0, h1[o]);
#pragma unroll
        for (int o = 0; o < 64; o++) h1[o] = fmaf(W1t[65 * 64 + o], xl1, h1[o]);
#pragma unroll
        for (int o = 0; o < 64; o++) h1[o] = fmaf(W1t[66 * 64 + o], xl2, h1[o]);
    }
#pragma unroll
    for (int o = 0; o < 64; o++) {
        float sc = g1[o] * rsqrtf(v1[o] + EPSF);
        h1[o] = fmaxf(fmaf(h1[o] + b1[o] - m1[o], sc, bt1[o]), 0.f);
    }

    // ----- layer 2: 64 -> 64 -----
    float h2[64];
#pragma unroll
    for (int o = 0; o < 64; o++) h2[o] = 0.f;
#pragma unroll
    for (int c = 0; c < 64; c++) {
        float hv = h1[c];
#pragma unroll
        for (int o = 0; o < 64; o++) h2[o] = fmaf(W2t[c * 64 + o], hv, h2[o]);
    }
#pragma unroll
    for (int o = 0; o < 64; o++) {
        float sc = g2[o] * rsqrtf(v2[o] + EPSF);
        h2[o] = fmaxf(fmaf(h2[o] + b2[o] - m2[o], sc, bt2[o]), 0.f);
    }

    // ----- layer 3: 64 -> 128, in 4 chunks of 32, fused masked max-pool -----
    for (int ch = 0; ch < 4; ch++) {
        float acc[32];
#pragma unroll
        for (int oo = 0; oo < 32; oo++) acc[oo] = 0.f;
#pragma unroll
        for (int c = 0; c < 64; c++) {
            float hv = h2[c];
#pragma unroll
            for (int oo = 0; oo < 32; oo++)
                acc[oo] = fmaf(W3t[c * 128 + ch * 32 + oo], hv, acc[oo]);
        }
#pragma unroll
        for (int oo = 0; oo < 32; oo++) {
            int o = ch * 32 + oo;
            float sc = g3[o] * rsqrtf(v3[o] + EPSF);
            float t = fmaxf(fmaf(acc[oo] + b3[o] - m3[o], sc, bt3[o]), 0.f);
            sred[wid][lane][oo] = valid ? t : -INFINITY;
        }
        __syncthreads();
        {
            int c = lane & 31, half = lane >> 5;
            float mx = -INFINITY;
#pragma unroll
            for (int r = 0; r < 32; r++) mx = fmaxf(mx, sred[wid][half * 32 + r][c]);
            mx = fmaxf(mx, __shfl_xor(mx, 32, 64));
            if (lane < 32) pooled[(size_t)id * 128 + ch * 32 + c] = mx;
        }
        __syncthreads();
    }
}

// ---------------------------------------------------------------------------
extern "C" void kernel_launch(void* const* d_in, const int* in_sizes, int n_in,
                              void* d_out, int out_size, void* d_ws, size_t ws_size,
                              hipStream_t stream) {
    const float* x  = (const float*)d_in[0];
    const float* xc = (const float*)d_in[1];
    const float* W1 = (const float*)d_in[2];
    const float* b1 = (const float*)d_in[3];
    const float* g1 = (const float*)d_in[4];
    const float* bt1 = (const float*)d_in[5];
    const float* m1 = (const float*)d_in[6];
    const float* v1 = (const float*)d_in[7];
    const float* W2 = (const float*)d_in[8];
    const float* b2 = (const float*)d_in[9];
    const float* g2 = (const float*)d_in[10];
    const float* bt2 = (const float*)d_in[11];
    const float* m2 = (const float*)d_in[12];
    const float* v2 = (const float*)d_in[13];
    const float* W3 = (const float*)d_in[14];
    const float* b3 = (const float*)d_in[15];
    const float* g3 = (const float*)d_in[16];
    const float* bt3 = (const float*)d_in[17];
    const float* m3 = (const float*)d_in[18];
    const float* v3 = (const float*)d_in[19];

    float* out = (float*)d_out;
    float* cen = out;                                   // [B,S,3]
    float* pooled = out + (size_t)BATCH * NSAMP * 3;    // [B,S,128]

    int* idxb = (int*)d_ws;                             // [B*S, K] = 2 MB
    float* W1t = (float*)((char*)d_ws + (size_t)BATCH * NSAMP * KNBR * 4);
    float* W2t = W1t + 67 * 64;
    float* W3t = W2t + 64 * 64;

    prep_kernel<<<1, 256, 0, stream>>>(W1, W2, W3, W1t, W2t, W3t);
    fps_kernel<<<BATCH, 512, 0, stream>>>(x, cen);
    ball_kernel<<<(BATCH * NSAMP) / 4, 256, 0, stream>>>(x, cen, idxb);
    mlp_kernel<<<(BATCH * NSAMP) / 4, 256, 0, stream>>>(
        x, xc, cen, idxb,
        W1t, b1, g1, bt1, m1, v1,
        W2t, b2, g2, bt2, m2, v2,
        W3t, b3, g3, bt3, m3, v3,
        pooled);
}

// Round 4
// 2429.114 us; speedup vs baseline: 1.1758x; 1.1758x over previous
//
#include <hip/hip_runtime.h>
#include <math.h>

#define BATCH 4
#define NPTS  8192
#define NSAMP 2048
#define KNBR  64
#define EPSF  1e-5f

// ---------------------------------------------------------------------------
// Kernel 0: transpose weights into ws so MLP reads are contiguous scalar loads
// ---------------------------------------------------------------------------
__global__ void prep_kernel(const float* __restrict__ W1, const float* __restrict__ W2,
                            const float* __restrict__ W3,
                            float* __restrict__ W1t, float* __restrict__ W2t,
                            float* __restrict__ W3t) {
    int t = threadIdx.x;
    for (int i = t; i < 64 * 67; i += 256) { int o = i / 67, c = i % 67; W1t[c * 64 + o] = W1[i]; }
    for (int i = t; i < 64 * 64; i += 256) { int o = i >> 6, c = i & 63; W2t[c * 64 + o] = W2[i]; }
    for (int i = t; i < 128 * 64; i += 256) { int o = i >> 6, c = i & 63; W3t[c * 128 + o] = W3[i]; }
}

// DPP-based wave64 max: rocPRIM pattern row_shr 1/2/4/8 + row_bcast 15/31,
// final max lands in lane 63. bound_ctrl=true zero-fills invalid lanes —
// safe for max of non-negative distances.
#define DPP_FMAX(v, ctrl)                                                            \
    do {                                                                             \
        int _t = __builtin_amdgcn_update_dpp(0, __float_as_int(v), ctrl, 0xf, 0xf, true); \
        (v) = fmaxf((v), __int_as_float(_t));                                        \
    } while (0)

// ---------------------------------------------------------------------------
// Kernel 1: farthest point sampling — one block per batch, 512 threads
// (8 waves, 2/SIMD), 16 points/thread in registers.
// Exact fp32 (no FMA contraction) to match numpy reference.
// Per step: NO global memory ops (index history in LDS, centroids written in
// bulk at the end — keeps vmcnt(0) drains out of the barrier). Wave argmax:
// DPP max reduce (VALU-pipe, no ds_swizzle) + readlane, index via
// ballot->lowest-lane (lane order == index order == jnp.argmax tie-break).
// Block stage: float4/int4 LDS partials + 3-level tree, lower wid wins ties.
// ONE __syncthreads per step via parity double-buffered partials.
// ---------------------------------------------------------------------------
__global__ __launch_bounds__(512) void fps_kernel(const float* __restrict__ x,
                                                  float* __restrict__ cen_out) {
    const int b = blockIdx.x;
    const int tid = threadIdx.x;
    const int lane = tid & 63;
    const int wid = tid >> 6;
    __shared__ float sx[NPTS], sy[NPTS], sz[NPTS];   // 96 KB
    __shared__ __align__(16) float pd[2][8];
    __shared__ __align__(16) int pi[2][8];
    __shared__ int hist[NSAMP];                       // 8 KB

    const float* xb = x + (size_t)b * NPTS * 3;
    for (int i = tid; i < NPTS; i += 512) {
        sx[i] = xb[3 * i + 0];
        sy[i] = xb[3 * i + 1];
        sz[i] = xb[3 * i + 2];
    }
    __syncthreads();

    // 16 points per thread, contiguous: p = tid*16 + j  (j increasing == idx increasing)
    float px[16], py[16], pz[16], dist[16];
#pragma unroll
    for (int j = 0; j < 16; j++) {
        int p = tid * 16 + j;
        px[j] = sx[p]; py[j] = sy[p]; pz[j] = sz[p];
        dist[j] = 1e10f;
    }

    int cur = 0;
    for (int s = 0; s < NSAMP; s++) {
        float cx = sx[cur], cy = sy[cur], cz = sz[cur];
        if (tid == 0) hist[s] = cur;
        float bestd = -1.0f;
        int bestj = 0;
#pragma unroll
        for (int j = 0; j < 16; j++) {
            float dx = __fsub_rn(px[j], cx);
            float dy = __fsub_rn(py[j], cy);
            float dz = __fsub_rn(pz[j], cz);
            float d = __fadd_rn(__fadd_rn(__fmul_rn(dx, dx), __fmul_rn(dy, dy)), __fmul_rn(dz, dz));
            float dm = fminf(dist[j], d);
            dist[j] = dm;
            if (dm > bestd) { bestd = dm; bestj = j; }   // strict >: lowest idx on tie
        }
        // wave argmax: DPP max reduce to lane 63, then uniform readback
        float w = bestd;
        DPP_FMAX(w, 0x111);   // row_shr:1
        DPP_FMAX(w, 0x112);   // row_shr:2
        DPP_FMAX(w, 0x114);   // row_shr:4
        DPP_FMAX(w, 0x118);   // row_shr:8
        DPP_FMAX(w, 0x142);   // row_bcast:15
        DPP_FMAX(w, 0x143);   // row_bcast:31
        float wmax = __int_as_float(__builtin_amdgcn_readlane(__float_as_int(w), 63));
        unsigned long long eq = __ballot(bestd == wmax);
        int src = __ffsll(eq) - 1;                       // lowest lane == lowest index
        int widx = __builtin_amdgcn_readlane(tid * 16 + bestj, src);
        const int p = s & 1;
        if (lane == 0) { pd[p][wid] = wmax; pi[p][wid] = widx; }
        __syncthreads();
        float4 da = *(const float4*)&pd[p][0];
        float4 db = *(const float4*)&pd[p][4];
        int4 ia = *(const int4*)&pi[p][0];
        int4 ib = *(const int4*)&pi[p][4];
        // 3-level tree; strict > on the higher-wid side keeps lowest wid on tie
        float d01 = da.x; int i01 = ia.x; if (da.y > d01) { d01 = da.y; i01 = ia.y; }
        float d23 = da.z; int i23 = ia.z; if (da.w > d23) { d23 = da.w; i23 = ia.w; }
        float d45 = db.x; int i45 = ib.x; if (db.y > d45) { d45 = db.y; i45 = ib.y; }
        float d67 = db.z; int i67 = ib.z; if (db.w > d67) { d67 = db.w; i67 = ib.w; }
        if (d23 > d01) { d01 = d23; i01 = i23; }
        if (d67 > d45) { d45 = d67; i45 = i67; }
        if (d45 > d01) { i01 = i45; }
        cur = i01;
    }

    // bulk centroid writeback (one-time; indices -> coords from LDS)
    __syncthreads();
    for (int i = tid; i < NSAMP; i += 512) {
        int idx = hist[i];
        float* o = cen_out + ((size_t)b * NSAMP + i) * 3;
        o[0] = sx[idx]; o[1] = sy[idx]; o[2] = sz[idx];
    }
}

// ---------------------------------------------------------------------------
// Kernel 2: ball query — one wave per centroid, ballot compaction, first-K in
// ascending index order (== top_k(-cand) semantics), -1 padded.
// ---------------------------------------------------------------------------
__global__ __launch_bounds__(256) void ball_kernel(const float* __restrict__ x,
                                                   const float* __restrict__ cen,
                                                   int* __restrict__ idxb) {
    const int wid = threadIdx.x >> 6, lane = threadIdx.x & 63;
    const int id = blockIdx.x * 4 + wid;           // 0..8191 == b*NSAMP+s
    const int b = id >> 11;
    const float r2 = (float)(0.2 * 0.2);
    const float cx = cen[3 * id], cy = cen[3 * id + 1], cz = cen[3 * id + 2];
    const float* xb = x + (size_t)b * NPTS * 3;

    int count = 0;
    for (int base = 0; base < NPTS && count < KNBR; base += 64) {
        int p = base + lane;
        float pxv = xb[3 * p], pyv = xb[3 * p + 1], pzv = xb[3 * p + 2];
        float dx = __fsub_rn(cx, pxv);
        float dy = __fsub_rn(cy, pyv);
        float dz = __fsub_rn(cz, pzv);
        float d2 = __fadd_rn(__fadd_rn(__fmul_rn(dx, dx), __fmul_rn(dy, dy)), __fmul_rn(dz, dz));
        bool hit = d2 < r2;
        unsigned long long m = __ballot(hit);
        if (hit) {
            int pos = count + __popcll(m & ((1ull << lane) - 1ull));
            if (pos < KNBR) idxb[(size_t)id * KNBR + pos] = p;
        }
        count += (int)__popcll(m);
    }
    for (int pos = count + lane; pos < KNBR; pos += 64)
        idxb[(size_t)id * KNBR + pos] = -1;
}

// ---------------------------------------------------------------------------
// Kernel 3: gather + 3x(conv1x1+BN+ReLU) + masked max pool.
// One wave per centroid, lane = neighbor. h1/h2 in registers; weights via
// wave-uniform scalar loads (transposed layout). Layer3 in 4 chunks of 32
// channels with per-wave LDS max-reduction across lanes.
// ---------------------------------------------------------------------------
__global__ __launch_bounds__(256) void mlp_kernel(
    const float* __restrict__ x, const float* __restrict__ xc,
    const float* __restrict__ cen, const int* __restrict__ idxb,
    const float* __restrict__ W1t, const float* __restrict__ b1, const float* __restrict__ g1,
    const float* __restrict__ bt1, const float* __restrict__ m1, const float* __restrict__ v1,
    const float* __restrict__ W2t, const float* __restrict__ b2, const float* __restrict__ g2,
    const float* __restrict__ bt2, const float* __restrict__ m2, const float* __restrict__ v2,
    const float* __restrict__ W3t, const float* __restrict__ b3, const float* __restrict__ g3,
    const float* __restrict__ bt3, const float* __restrict__ m3, const float* __restrict__ v3,
    float* __restrict__ pooled) {
    const int wid = threadIdx.x >> 6, lane = threadIdx.x & 63;
    const int id = blockIdx.x * 4 + wid;            // b*NSAMP + s
    const int b = id >> 11;
    __shared__ float sred[4][64][33];

    int il = idxb[(size_t)id * KNBR + lane];
    bool valid = il >= 0;
    int ik = valid ? il : 0;

    float cx = cen[3 * id], cy = cen[3 * id + 1], cz = cen[3 * id + 2];
    const float* xp = x + ((size_t)b * NPTS + ik) * 3;
    const float* xcp = xc + ((size_t)b * NPTS + ik) * 64;

    // ----- layer 1: 67 -> 64 -----
    float h1[64];
#pragma unroll
    for (int o = 0; o < 64; o++) h1[o] = 0.f;
#pragma unroll
    for (int c4 = 0; c4 < 16; c4++) {
        float4 t = ((const float4*)xcp)[c4];
        float tv0 = t.x, tv1 = t.y, tv2 = t.z, tv3 = t.w;
#pragma unroll
        for (int o = 0; o < 64; o++) h1[o] = fmaf(W1t[(c4 * 4 + 0) * 64 + o], tv0, h1[o]);
#pragma unroll
        for (int o = 0; o < 64; o++) h1[o] = fmaf(W1t[(c4 * 4 + 1) * 64 + o], tv1, h1[o]);
#pragma unroll
        for (int o = 0; o < 64; o++) h1[o] = fmaf(W1t[(c4 * 4 + 2) * 64 + o], tv2, h1[o]);
#pragma unroll
        for (int o = 0; o < 64; o++) h1[o] = fmaf(W1t[(c4 * 4 + 3) * 64 + o], tv3, h1[o]);
    }
    {
        float xl0 = xp[0] - cx, xl1 = xp[1] - cy, xl2 = xp[2] - cz;
#pragma unroll
        for (int o = 0; o < 64; o++) h1[o] = fmaf(W1t[64 * 64 + o], xl0, h1[o]);
#pragma unroll
        for (int o = 0; o < 64; o++) h1[o] = fmaf(W1t[65 * 64 + o], xl1, h1[o]);
#pragma unroll
        for (int o = 0; o < 64; o++) h1[o] = fmaf(W1t[66 * 64 + o], xl2, h1[o]);
    }
#pragma unroll
    for (int o = 0; o < 64; o++) {
        float sc = g1[o] * rsqrtf(v1[o] + EPSF);
        h1[o] = fmaxf(fmaf(h1[o] + b1[o] - m1[o], sc, bt1[o]), 0.f);
    }

    // ----- layer 2: 64 -> 64 -----
    float h2[64];
#pragma unroll
    for (int o = 0; o < 64; o++) h2[o] = 0.f;
#pragma unroll
    for (int c = 0; c < 64; c++) {
        float hv = h1[c];
#pragma unroll
        for (int o = 0; o < 64; o++) h2[o] = fmaf(W2t[c * 64 + o], hv, h2[o]);
    }
#pragma unroll
    for (int o = 0; o < 64; o++) {
        float sc = g2[o] * rsqrtf(v2[o] + EPSF);
        h2[o] = fmaxf(fmaf(h2[o] + b2[o] - m2[o], sc, bt2[o]), 0.f);
    }

    // ----- layer 3: 64 -> 128, in 4 chunks of 32, fused masked max-pool -----
    for (int ch = 0; ch < 4; ch++) {
        float acc[32];
#pragma unroll
        for (int oo = 0; oo < 32; oo++) acc[oo] = 0.f;
#pragma unroll
        for (int c = 0; c < 64; c++) {
            float hv = h2[c];
#pragma unroll
            for (int oo = 0; oo < 32; oo++)
                acc[oo] = fmaf(W3t[c * 128 + ch * 32 + oo], hv, acc[oo]);
        }
#pragma unroll
        for (int oo = 0; oo < 32; oo++) {
            int o = ch * 32 + oo;
            float sc = g3[o] * rsqrtf(v3[o] + EPSF);
            float t = fmaxf(fmaf(acc[oo] + b3[o] - m3[o], sc, bt3[o]), 0.f);
            sred[wid][lane][oo] = valid ? t : -INFINITY;
        }
        __syncthreads();
        {
            int c = lane & 31, half = lane >> 5;
            float mx = -INFINITY;
#pragma unroll
            for (int r = 0; r < 32; r++) mx = fmaxf(mx, sred[wid][half * 32 + r][c]);
            mx = fmaxf(mx, __shfl_xor(mx, 32, 64));
            if (lane < 32) pooled[(size_t)id * 128 + ch * 32 + c] = mx;
        }
        __syncthreads();
    }
}

// ---------------------------------------------------------------------------
extern "C" void kernel_launch(void* const* d_in, const int* in_sizes, int n_in,
                              void* d_out, int out_size, void* d_ws, size_t ws_size,
                              hipStream_t stream) {
    const float* x  = (const float*)d_in[0];
    const float* xc = (const float*)d_in[1];
    const float* W1 = (const float*)d_in[2];
    const float* b1 = (const float*)d_in[3];
    const float* g1 = (const float*)d_in[4];
    const float* bt1 = (const float*)d_in[5];
    const float* m1 = (const float*)d_in[6];
    const float* v1 = (const float*)d_in[7];
    const float* W2 = (const float*)d_in[8];
    const float* b2 = (const float*)d_in[9];
    const float* g2 = (const float*)d_in[10];
    const float* bt2 = (const float*)d_in[11];
    const float* m2 = (const float*)d_in[12];
    const float* v2 = (const float*)d_in[13];
    const float* W3 = (const float*)d_in[14];
    const float* b3 = (const float*)d_in[15];
    const float* g3 = (const float*)d_in[16];
    const float* bt3 = (const float*)d_in[17];
    const float* m3 = (const float*)d_in[18];
    const float* v3 = (const float*)d_in[19];

    float* out = (float*)d_out;
    float* cen = out;                                   // [B,S,3]
    float* pooled = out + (size_t)BATCH * NSAMP * 3;    // [B,S,128]

    int* idxb = (int*)d_ws;                             // [B*S, K] = 2 MB
    float* W1t = (float*)((char*)d_ws + (size_t)BATCH * NSAMP * KNBR * 4);
    float* W2t = W1t + 67 * 64;
    float* W3t = W2t + 64 * 64;

    prep_kernel<<<1, 256, 0, stream>>>(W1, W2, W3, W1t, W2t, W3t);
    fps_kernel<<<BATCH, 512, 0, stream>>>(x, cen);
    ball_kernel<<<(BATCH * NSAMP) / 4, 256, 0, stream>>>(x, cen, idxb);
    mlp_kernel<<<(BATCH * NSAMP) / 4, 256, 0, stream>>>(
        x, xc, cen, idxb,
        W1t, b1, g1, bt1, m1, v1,
        W2t, b2, g2, bt2, m2, v2,
        W3t, b3, g3, bt3, m3, v3,
        pooled);
}

// Round 5
// 2419.213 us; speedup vs baseline: 1.1806x; 1.0041x over previous
//
#include <hip/hip_runtime.h>
#include <math.h>

#define BATCH 4
#define NPTS  8192
#define NSAMP 2048
#define KNBR  64
#define EPSF  1e-5f

typedef float v2f __attribute__((ext_vector_type(2)));

// ---------------------------------------------------------------------------
// Kernel 0: transpose weights into ws so MLP reads are contiguous scalar loads
// ---------------------------------------------------------------------------
__global__ void prep_kernel(const float* __restrict__ W1, const float* __restrict__ W2,
                            const float* __restrict__ W3,
                            float* __restrict__ W1t, float* __restrict__ W2t,
                            float* __restrict__ W3t) {
    int t = threadIdx.x;
    for (int i = t; i < 64 * 67; i += 256) { int o = i / 67, c = i % 67; W1t[c * 64 + o] = W1[i]; }
    for (int i = t; i < 64 * 64; i += 256) { int o = i >> 6, c = i & 63; W2t[c * 64 + o] = W2[i]; }
    for (int i = t; i < 128 * 64; i += 256) { int o = i >> 6, c = i & 63; W3t[c * 128 + o] = W3[i]; }
}

// DPP-based wave64 max: row_shr 1/2/4/8 + row_bcast 15/31; full max in lane 63.
// bound_ctrl=true zero-fills — safe for max of non-negative distances.
#define DPP_FMAX(v, ctrl)                                                            \
    do {                                                                             \
        int _t = __builtin_amdgcn_update_dpp(0, __float_as_int(v), ctrl, 0xf, 0xf, true); \
        (v) = fmaxf((v), __int_as_float(_t));                                        \
    } while (0)

// ---------------------------------------------------------------------------
// Kernel 1: farthest point sampling — one block per batch, 512 threads
// (8 waves, 2/SIMD), 16 points/thread in packed fp32 pairs (v_pk_* ops).
// contract(off) => plain IEEE rn mul/add, bit-identical to the numpy ref.
// Hot loop tracks the max VALUE only (no per-point argmax bookkeeping).
// Index recovery after block max known: threads holding dist==bmax do
// atomicMin(LDS, global index) — min over maxima == jnp.argmax first-max
// tie-break, exactly. Two barriers/step, parity-buffered atomic slot.
// No global memory ops in the loop (hist in LDS, bulk writeback at end).
// ---------------------------------------------------------------------------
__global__ __launch_bounds__(512) void fps_kernel(const float* __restrict__ x,
                                                  float* __restrict__ cen_out) {
#pragma clang fp contract(off)
    const int b = blockIdx.x;
    const int tid = threadIdx.x;
    const int lane = tid & 63;
    const int wid = tid >> 6;
    __shared__ float sx[NPTS], sy[NPTS], sz[NPTS];   // 96 KB
    __shared__ __align__(16) float pd[2][8];
    __shared__ int pi[2];
    __shared__ int hist[NSAMP];                       // 8 KB

    const float* xb = x + (size_t)b * NPTS * 3;
    for (int i = tid; i < NPTS; i += 512) {
        sx[i] = xb[3 * i + 0];
        sy[i] = xb[3 * i + 1];
        sz[i] = xb[3 * i + 2];
    }
    if (tid == 0) { pi[0] = 0x7fffffff; pi[1] = 0x7fffffff; }
    __syncthreads();

    // 16 points per thread as 8 packed pairs: pair j holds p = tid*16+2j, +1
    v2f px[8], py[8], pz[8], dist[8];
#pragma unroll
    for (int j = 0; j < 8; j++) {
        int p = tid * 16 + 2 * j;
        px[j] = (v2f){sx[p], sx[p + 1]};
        py[j] = (v2f){sy[p], sy[p + 1]};
        pz[j] = (v2f){sz[p], sz[p + 1]};
        dist[j] = (v2f){1e10f, 1e10f};
    }

    int cur = 0;
    for (int s = 0; s < NSAMP; s++) {
        float cx = sx[cur], cy = sy[cur], cz = sz[cur];
        if (tid == 0) hist[s] = cur;
        const v2f cvx = (v2f){cx, cx}, cvy = (v2f){cy, cy}, cvz = (v2f){cz, cz};
        v2f m = (v2f){-1.0f, -1.0f};
#pragma unroll
        for (int j = 0; j < 8; j++) {
            v2f dx = px[j] - cvx;
            v2f dy = py[j] - cvy;
            v2f dz = pz[j] - cvz;
            v2f d = ((dx * dx) + (dy * dy)) + (dz * dz);   // contract(off): exact rn
            v2f dm;
            dm.x = fminf(dist[j].x, d.x);
            dm.y = fminf(dist[j].y, d.y);
            dist[j] = dm;
            m.x = fmaxf(m.x, dm.x);
            m.y = fmaxf(m.y, dm.y);
        }
        float bestd = fmaxf(m.x, m.y);
        // wave max via DPP; full max lands in lane 63
        float w = bestd;
        DPP_FMAX(w, 0x111);   // row_shr:1
        DPP_FMAX(w, 0x112);   // row_shr:2
        DPP_FMAX(w, 0x114);   // row_shr:4
        DPP_FMAX(w, 0x118);   // row_shr:8
        DPP_FMAX(w, 0x142);   // row_bcast:15
        DPP_FMAX(w, 0x143);   // row_bcast:31
        const int p = s & 1;
        if (lane == 63) pd[p][wid] = w;
        __syncthreads();                                   // bar1: partials ready
        float4 da = *(const float4*)&pd[p][0];
        float4 db = *(const float4*)&pd[p][4];
        float bmax = fmaxf(fmaxf(fmaxf(da.x, da.y), fmaxf(da.z, da.w)),
                           fmaxf(fmaxf(db.x, db.y), fmaxf(db.z, db.w)));
        if (tid == 0) pi[1 - p] = 0x7fffffff;              // reset other slot
        // index recovery: lowest global index holding bmax (exact argmax tie-break)
        int local = 0x7fffffff;
#pragma unroll
        for (int j = 0; j < 8; j++) {
            if (dist[j].x == bmax) local = min(local, tid * 16 + 2 * j);
            if (dist[j].y == bmax) local = min(local, tid * 16 + 2 * j + 1);
        }
        if (local != 0x7fffffff) atomicMin(&pi[p], local);
        __syncthreads();                                   // bar2: winner published
        cur = pi[p];
    }

    // bulk centroid writeback (one-time; indices -> coords from LDS)
    __syncthreads();
    for (int i = tid; i < NSAMP; i += 512) {
        int idx = hist[i];
        float* o = cen_out + ((size_t)b * NSAMP + i) * 3;
        o[0] = sx[idx]; o[1] = sy[idx]; o[2] = sz[idx];
    }
}

// ---------------------------------------------------------------------------
// Kernel 2: ball query — one wave per centroid, ballot compaction, first-K in
// ascending index order (== top_k(-cand) semantics), -1 padded.
// ---------------------------------------------------------------------------
__global__ __launch_bounds__(256) void ball_kernel(const float* __restrict__ x,
                                                   const float* __restrict__ cen,
                                                   int* __restrict__ idxb) {
    const int wid = threadIdx.x >> 6, lane = threadIdx.x & 63;
    const int id = blockIdx.x * 4 + wid;           // 0..8191 == b*NSAMP+s
    const int b = id >> 11;
    const float r2 = (float)(0.2 * 0.2);
    const float cx = cen[3 * id], cy = cen[3 * id + 1], cz = cen[3 * id + 2];
    const float* xb = x + (size_t)b * NPTS * 3;

    int count = 0;
    for (int base = 0; base < NPTS && count < KNBR; base += 64) {
        int p = base + lane;
        float pxv = xb[3 * p], pyv = xb[3 * p + 1], pzv = xb[3 * p + 2];
        float dx = __fsub_rn(cx, pxv);
        float dy = __fsub_rn(cy, pyv);
        float dz = __fsub_rn(cz, pzv);
        float d2 = __fadd_rn(__fadd_rn(__fmul_rn(dx, dx), __fmul_rn(dy, dy)), __fmul_rn(dz, dz));
        bool hit = d2 < r2;
        unsigned long long m = __ballot(hit);
        if (hit) {
            int pos = count + __popcll(m & ((1ull << lane) - 1ull));
            if (pos < KNBR) idxb[(size_t)id * KNBR + pos] = p;
        }
        count += (int)__popcll(m);
    }
    for (int pos = count + lane; pos < KNBR; pos += 64)
        idxb[(size_t)id * KNBR + pos] = -1;
}

// ---------------------------------------------------------------------------
// Kernel 3: gather + 3x(conv1x1+BN+ReLU) + masked max pool.
// One wave per centroid, lane = neighbor. h1/h2 in registers; weights via
// wave-uniform scalar loads (transposed layout). Layer3 in 4 chunks of 32
// channels with per-wave LDS max-reduction across lanes.
// ---------------------------------------------------------------------------
__global__ __launch_bounds__(256) void mlp_kernel(
    const float* __restrict__ x, const float* __restrict__ xc,
    const float* __restrict__ cen, const int* __restrict__ idxb,
    const float* __restrict__ W1t, const float* __restrict__ b1, const float* __restrict__ g1,
    const float* __restrict__ bt1, const float* __restrict__ m1, const float* __restrict__ v1,
    const float* __restrict__ W2t, const float* __restrict__ b2, const float* __restrict__ g2,
    const float* __restrict__ bt2, const float* __restrict__ m2, const float* __restrict__ v2,
    const float* __restrict__ W3t, const float* __restrict__ b3, const float* __restrict__ g3,
    const float* __restrict__ bt3, const float* __restrict__ m3, const float* __restrict__ v3,
    float* __restrict__ pooled) {
    const int wid = threadIdx.x >> 6, lane = threadIdx.x & 63;
    const int id = blockIdx.x * 4 + wid;            // b*NSAMP + s
    const int b = id >> 11;
    __shared__ float sred[4][64][33];

    int il = idxb[(size_t)id * KNBR + lane];
    bool valid = il >= 0;
    int ik = valid ? il : 0;

    float cx = cen[3 * id], cy = cen[3 * id + 1], cz = cen[3 * id + 2];
    const float* xp = x + ((size_t)b * NPTS + ik) * 3;
    const float* xcp = xc + ((size_t)b * NPTS + ik) * 64;

    // ----- layer 1: 67 -> 64 -----
    float h1[64];
#pragma unroll
    for (int o = 0; o < 64; o++) h1[o] = 0.f;
#pragma unroll
    for (int c4 = 0; c4 < 16; c4++) {
        float4 t = ((const float4*)xcp)[c4];
        float tv0 = t.x, tv1 = t.y, tv2 = t.z, tv3 = t.w;
#pragma unroll
        for (int o = 0; o < 64; o++) h1[o] = fmaf(W1t[(c4 * 4 + 0) * 64 + o], tv0, h1[o]);
#pragma unroll
        for (int o = 0; o < 64; o++) h1[o] = fmaf(W1t[(c4 * 4 + 1) * 64 + o], tv1, h1[o]);
#pragma unroll
        for (int o = 0; o < 64; o++) h1[o] = fmaf(W1t[(c4 * 4 + 2) * 64 + o], tv2, h1[o]);
#pragma unroll
        for (int o = 0; o < 64; o++) h1[o] = fmaf(W1t[(c4 * 4 + 3) * 64 + o], tv3, h1[o]);
    }
    {
        float xl0 = xp[0] - cx, xl1 = xp[1] - cy, xl2 = xp[2] - cz;
#pragma unroll
        for (int o = 0; o < 64; o++) h1[o] = fmaf(W1t[64 * 64 + o], xl0, h1[o]);
#pragma unroll
        for (int o = 0; o < 64; o++) h1[o] = fmaf(W1t[65 * 64 + o], xl1, h1[o]);
#pragma unroll
        for (int o = 0; o < 64; o++) h1[o] = fmaf(W1t[66 * 64 + o], xl2, h1[o]);
    }
#pragma unroll
    for (int o = 0; o < 64; o++) {
        float sc = g1[o] * rsqrtf(v1[o] + EPSF);
        h1[o] = fmaxf(fmaf(h1[o] + b1[o] - m1[o], sc, bt1[o]), 0.f);
    }

    // ----- layer 2: 64 -> 64 -----
    float h2[64];
#pragma unroll
    for (int o = 0; o < 64; o++) h2[o] = 0.f;
#pragma unroll
    for (int c = 0; c < 64; c++) {
        float hv = h1[c];
#pragma unroll
        for (int o = 0; o < 64; o++) h2[o] = fmaf(W2t[c * 64 + o], hv, h2[o]);
    }
#pragma unroll
    for (int o = 0; o < 64; o++) {
        float sc = g2[o] * rsqrtf(v2[o] + EPSF);
        h2[o] = fmaxf(fmaf(h2[o] + b2[o] - m2[o], sc, bt2[o]), 0.f);
    }

    // ----- layer 3: 64 -> 128, in 4 chunks of 32, fused masked max-pool -----
    for (int ch = 0; ch < 4; ch++) {
        float acc[32];
#pragma unroll
        for (int oo = 0; oo < 32; oo++) acc[oo] = 0.f;
#pragma unroll
        for (int c = 0; c < 64; c++) {
            float hv = h2[c];
#pragma unroll
            for (int oo = 0; oo < 32; oo++)
                acc[oo] = fmaf(W3t[c * 128 + ch * 32 + oo], hv, acc[oo]);
        }
#pragma unroll
        for (int oo = 0; oo < 32; oo++) {
            int o = ch * 32 + oo;
            float sc = g3[o] * rsqrtf(v3[o] + EPSF);
            float t = fmaxf(fmaf(acc[oo] + b3[o] - m3[o], sc, bt3[o]), 0.f);
            sred[wid][lane][oo] = valid ? t : -INFINITY;
        }
        __syncthreads();
        {
            int c = lane & 31, half = lane >> 5;
            float mx = -INFINITY;
#pragma unroll
            for (int r = 0; r < 32; r++) mx = fmaxf(mx, sred[wid][half * 32 + r][c]);
            mx = fmaxf(mx, __shfl_xor(mx, 32, 64));
            if (lane < 32) pooled[(size_t)id * 128 + ch * 32 + c] = mx;
        }
        __syncthreads();
    }
}

// ---------------------------------------------------------------------------
extern "C" void kernel_launch(void* const* d_in, const int* in_sizes, int n_in,
                              void* d_out, int out_size, void* d_ws, size_t ws_size,
                              hipStream_t stream) {
    const float* x  = (const float*)d_in[0];
    const float* xc = (const float*)d_in[1];
    const float* W1 = (const float*)d_in[2];
    const float* b1 = (const float*)d_in[3];
    const float* g1 = (const float*)d_in[4];
    const float* bt1 = (const float*)d_in[5];
    const float* m1 = (const float*)d_in[6];
    const float* v1 = (const float*)d_in[7];
    const float* W2 = (const float*)d_in[8];
    const float* b2 = (const float*)d_in[9];
    const float* g2 = (const float*)d_in[10];
    const float* bt2 = (const float*)d_in[11];
    const float* m2 = (const float*)d_in[12];
    const float* v2 = (const float*)d_in[13];
    const float* W3 = (const float*)d_in[14];
    const float* b3 = (const float*)d_in[15];
    const float* g3 = (const float*)d_in[16];
    const float* bt3 = (const float*)d_in[17];
    const float* m3 = (const float*)d_in[18];
    const float* v3 = (const float*)d_in[19];

    float* out = (float*)d_out;
    float* cen = out;                                   // [B,S,3]
    float* pooled = out + (size_t)BATCH * NSAMP * 3;    // [B,S,128]

    int* idxb = (int*)d_ws;                             // [B*S, K] = 2 MB
    float* W1t = (float*)((char*)d_ws + (size_t)BATCH * NSAMP * KNBR * 4);
    float* W2t = W1t + 67 * 64;
    float* W3t = W2t + 64 * 64;

    prep_kernel<<<1, 256, 0, stream>>>(W1, W2, W3, W1t, W2t, W3t);
    fps_kernel<<<BATCH, 512, 0, stream>>>(x, cen);
    ball_kernel<<<(BATCH * NSAMP) / 4, 256, 0, stream>>>(x, cen, idxb);
    mlp_kernel<<<(BATCH * NSAMP) / 4, 256, 0, stream>>>(
        x, xc, cen, idxb,
        W1t, b1, g1, bt1, m1, v1,
        W2t, b2, g2, bt2, m2, v2,
        W3t, b3, g3, bt3, m3, v3,
        pooled);
}